// Round 21
// baseline (449.715 us; speedup 1.0000x reference)
//
#include <hip/hip_runtime.h>
#include <math.h>

#define NPIX 50176      // 16*56*56
#define CDIM 384
#define HEADS 6
#define NLOGIT 54       // HEADS*9
#define HH 56
#define WW 56
#define KSTEPS 12       // CDIM/32
#define NCH_V 28        // total fragment chunks (448 cols / 16)
#define NCH_P 24        // proj fragment chunks (384 cols / 16)

typedef __attribute__((ext_vector_type(8))) __bf16 bf16x8;
typedef __attribute__((ext_vector_type(4))) float f32x4;

__device__ __forceinline__ void glds16(const void* g, void* l) {
  __builtin_amdgcn_global_load_lds(
      (const __attribute__((address_space(1))) unsigned int*)g,
      (__attribute__((address_space(3))) unsigned int*)l, 16, 0, 0);
}

// ---------------------------------------------------------------------------
// Prep: fragment-major weights (unchanged, proven).
// ---------------------------------------------------------------------------
__global__ __launch_bounds__(256) void prep_kernel(
    const float* __restrict__ W_v, const float* __restrict__ W_proj,
    const float* __restrict__ W_attn, const float* __restrict__ b_attn,
    __bf16* __restrict__ Wcat_frag, __bf16* __restrict__ Wtp_frag,
    float* __restrict__ bpad) {
  const int gid = blockIdx.x * 256 + threadIdx.x;
  const int NV = KSTEPS * NCH_V * 64;   // 21504
  const int NP = KSTEPS * NCH_P * 64;   // 18432
  if (gid < NV) {
    const int ks   = gid / (NCH_V * 64);
    const int rem  = gid % (NCH_V * 64);
    const int ni   = rem >> 6;
    const int lane = rem & 63;
    const int n  = ni * 16 + (lane & 15);
    const int kb = ks * 32 + (lane >> 4) * 8;
    bf16x8 o;
    #pragma unroll
    for (int q = 0; q < 8; ++q) {
      const int k = kb + q;
      float val;
      if (n < CDIM) val = W_v[k * CDIM + n];
      else {
        const int nn = n - CDIM;
        val = (nn < NLOGIT) ? W_attn[k * NLOGIT + nn] : 0.f;
      }
      o[q] = (__bf16)val;
    }
    *(bf16x8*)&Wcat_frag[(size_t)gid * 8] = o;
  } else if (gid < NV + NP) {
    const int r    = gid - NV;
    const int ks   = r / (NCH_P * 64);
    const int rem  = r % (NCH_P * 64);
    const int ni   = rem >> 6;
    const int lane = rem & 63;
    const int n  = ni * 16 + (lane & 15);
    const int kb = ks * 32 + (lane >> 4) * 8;
    bf16x8 o;
    #pragma unroll
    for (int q = 0; q < 8; ++q) o[q] = (__bf16)W_proj[(kb + q) * CDIM + n];
    *(bf16x8*)&Wtp_frag[(size_t)r * 8] = o;
  } else if (gid < NV + NP + 64) {
    const int n = gid - NV - NP;
    bpad[n] = (n < NLOGIT) ? b_attn[n] : 0.f;
  }
}

// ---------------------------------------------------------------------------
// Merged v + logit GEMM (r13 structure): grid (NPIX/64, 2), 14 chunks/panel.
// fp32 A per-lane (2x float4 + cvt, 1-step prefetch), B fragment-major via
// glds16, double-buffer with plain __syncthreads (proven race-free, 65us).
// NEW: coalesced epilogue via per-wave LDS transpose (bf16x8 stores).
// by=1 chunks 10..13 are logit cols -> softmax -> attn.
// ---------------------------------------------------------------------------
__global__ __launch_bounds__(256) void gemm_v_logit_kernel(
    const float* __restrict__ X, const __bf16* __restrict__ Wcat_frag,
    const float* __restrict__ b_v, __bf16* __restrict__ v,
    const float* __restrict__ bpad, float* __restrict__ attn) {
  __shared__ __bf16 Bs[2 * 14 * 512];            // 28672B
  float (*Ls)[68] = (float(*)[68])Bs;            // logit overlay (17408B)

  const int tid  = threadIdx.x;
  const int wave = tid >> 6;
  const int lane = tid & 63;
  const int bm   = blockIdx.x * 64;
  const int by   = blockIdx.y;                   // 0 or 1
  const int nbase = by * 14;
  const int frow = lane & 15;
  const int fk8  = (lane >> 4) * 8;

  const int arow = bm + wave * 16 + frow;
  const float* xrow = X + (size_t)arow * CDIM + fk8;

  f32x4 acc[14] = {};

  // prologue: stage(0) -> buf0, prefetch A(0)
  #pragma unroll
  for (int c = 0; c < 4; ++c) {
    const int chunk = wave * 4 + c;
    if (chunk < 14)
      glds16(Wcat_frag + ((size_t)(nbase + chunk) * 64 + lane) * 8,
             (__bf16*)Bs + chunk * 512);
  }
  float4 pf0 = *(const float4*)(xrow + 0);
  float4 pf1 = *(const float4*)(xrow + 4);
  __syncthreads();

  int buf = 0;
  for (int ks = 0; ks < KSTEPS; ++ks) {
    if (ks + 1 < KSTEPS) {
      __bf16* dst = Bs + (buf ^ 1) * 14 * 512;
      #pragma unroll
      for (int c = 0; c < 4; ++c) {
        const int chunk = wave * 4 + c;
        if (chunk < 14)
          glds16(Wcat_frag +
                     ((size_t)((ks + 1) * NCH_V + nbase + chunk) * 64 + lane) * 8,
                 dst + chunk * 512);
      }
    }
    bf16x8 a;
    a[0] = (__bf16)pf0.x; a[1] = (__bf16)pf0.y; a[2] = (__bf16)pf0.z; a[3] = (__bf16)pf0.w;
    a[4] = (__bf16)pf1.x; a[5] = (__bf16)pf1.y; a[6] = (__bf16)pf1.z; a[7] = (__bf16)pf1.w;
    if (ks + 1 < KSTEPS) {
      pf0 = *(const float4*)(xrow + (ks + 1) * 32 + 0);
      pf1 = *(const float4*)(xrow + (ks + 1) * 32 + 4);
    }

    const __bf16* Bc = Bs + buf * 14 * 512;
    #pragma unroll
    for (int ni = 0; ni < 14; ++ni) {
      const bf16x8 b = *(const bf16x8*)&Bc[(ni * 64 + lane) * 8];
      acc[ni] = __builtin_amdgcn_mfma_f32_16x16x32_bf16(a, b, acc[ni], 0, 0, 0);
    }
    __syncthreads();
    buf ^= 1;
  }

  // ---- coalesced v epilogue: per-wave LDS transpose, 4-chunk passes ----
  const int orow = (lane >> 4) * 4;
  const int nv = (by == 0) ? 14 : 10;
  float (*Lw)[68] = (float(*)[68])((float*)Bs + wave * 16 * 68);  // 4352B/wave

  for (int c0 = 0; c0 < nv; c0 += 4) {
    const int pc = (nv - c0 < 4) ? (nv - c0) : 4;   // 4 or 2 (block-uniform)
    for (int i = 0; i < pc; ++i) {
      const int ni = c0 + i;
      const float bvl = b_v[(nbase + ni) * 16 + frow];
      #pragma unroll
      for (int r = 0; r < 4; ++r)
        Lw[orow + r][i * 16 + frow] = acc[ni][r] + bvl;
    }
    __syncthreads();
    const int ngrp  = pc * 2;          // bf16x8 groups per row
    const int ntask = 16 * ngrp;
    for (int t = lane; t < ntask; t += 64) {
      const int r_ = t / ngrp, g = t % ngrp;
      bf16x8 o;
      #pragma unroll
      for (int q = 0; q < 8; ++q) o[q] = (__bf16)Lw[r_][g * 8 + q];
      *(bf16x8*)&v[(size_t)(bm + wave * 16 + r_) * CDIM +
                   (nbase + c0) * 16 + g * 8] = o;
    }
    __syncthreads();
  }

  if (by == 1) {
    // logit chunks 10..13 -> Ls -> softmax -> attn
    float bvl[4];
    #pragma unroll
    for (int ni = 0; ni < 4; ++ni) bvl[ni] = bpad[ni * 16 + frow];
    #pragma unroll
    for (int ni = 0; ni < 4; ++ni)
      #pragma unroll
      for (int r = 0; r < 4; ++r)
        Ls[wave * 16 + orow + r][ni * 16 + frow] = acc[10 + ni][r] + bvl[ni];
    __syncthreads();

    #pragma unroll
    for (int it = 0; it < 2; ++it) {
      const int task = it * 256 + tid;
      if (task < 64 * HEADS) {
        const int pl = task / HEADS;
        const int h  = task % HEADS;
        const float* row = &Ls[pl][h * 9];
        float m = row[0];
        #pragma unroll
        for (int w = 1; w < 9; ++w) m = fmaxf(m, row[w]);
        float e[9], s = 0.f;
        #pragma unroll
        for (int w = 0; w < 9; ++w) { e[w] = __expf(row[w] - m); s += e[w]; }
        const float inv = 1.f / s;
        float* op = &attn[(size_t)(bm + pl) * NLOGIT + h * 9];
        #pragma unroll
        for (int w = 0; w < 9; ++w) op[w] = e[w] * inv;
      }
    }
  }
}

// ---------------------------------------------------------------------------
// Proj GEMM (r13 structure): grid (NPIX/64, 2), 12 chunks, dbuf plain sync.
// NEW: coalesced fp32 epilogue via per-wave LDS transpose (float4 stores).
// ---------------------------------------------------------------------------
__global__ __launch_bounds__(256) void gemm_proj_kernel(
    const __bf16* __restrict__ Y, const __bf16* __restrict__ Wtp_frag,
    const float* __restrict__ bias, float* __restrict__ Out) {
  __shared__ __bf16 Bs[2 * 12 * 512];   // 24576B

  const int tid  = threadIdx.x;
  const int wave = tid >> 6;
  const int lane = tid & 63;
  const int bm   = blockIdx.x * 64;
  const int by   = blockIdx.y;
  const int nbase = by * 12;
  const int frow = lane & 15;
  const int fk8  = (lane >> 4) * 8;

  const int arow = bm + wave * 16 + frow;
  const __bf16* yrow = Y + (size_t)arow * CDIM + fk8;

  f32x4 acc[12] = {};

  #pragma unroll
  for (int c = 0; c < 3; ++c) {
    const int chunk = wave * 3 + c;
    glds16(Wtp_frag + ((size_t)(nbase + chunk) * 64 + lane) * 8,
           Bs + chunk * 512);
  }
  bf16x8 a = *(const bf16x8*)yrow;
  __syncthreads();

  int buf = 0;
  for (int ks = 0; ks < KSTEPS; ++ks) {
    if (ks + 1 < KSTEPS) {
      __bf16* dst = Bs + (buf ^ 1) * 12 * 512;
      #pragma unroll
      for (int c = 0; c < 3; ++c) {
        const int chunk = wave * 3 + c;
        glds16(Wtp_frag +
                   ((size_t)((ks + 1) * NCH_P + nbase + chunk) * 64 + lane) * 8,
               dst + chunk * 512);
      }
    }
    bf16x8 a_next;
    if (ks + 1 < KSTEPS) a_next = *(const bf16x8*)(yrow + (ks + 1) * 32);

    const __bf16* Bc = Bs + buf * 12 * 512;
    #pragma unroll
    for (int ni = 0; ni < 12; ++ni) {
      const bf16x8 b = *(const bf16x8*)&Bc[(ni * 64 + lane) * 8];
      acc[ni] = __builtin_amdgcn_mfma_f32_16x16x32_bf16(a, b, acc[ni], 0, 0, 0);
    }
    __syncthreads();
    buf ^= 1;
    a = a_next;
  }

  // ---- coalesced fp32 epilogue: per-wave LDS transpose, 4-chunk passes ----
  const int orow = (lane >> 4) * 4;
  float (*Lw)[68] = (float(*)[68])((float*)Bs + wave * 16 * 68);  // 4352B/wave

  for (int c0 = 0; c0 < 12; c0 += 4) {
    #pragma unroll
    for (int i = 0; i < 4; ++i) {
      const int ni = c0 + i;
      const float bvl = bias[(nbase + ni) * 16 + frow];
      #pragma unroll
      for (int r = 0; r < 4; ++r)
        Lw[orow + r][i * 16 + frow] = acc[ni][r] + bvl;
    }
    __syncthreads();
    // 16 rows x 16 float4-groups = 256 tasks, 4 per lane
    #pragma unroll
    for (int it = 0; it < 4; ++it) {
      const int t  = it * 64 + lane;
      const int r_ = t >> 4, g = t & 15;
      const float4 o = *(const float4*)&Lw[r_][g * 4];
      *(float4*)&Out[(size_t)(bm + wave * 16 + r_) * CDIM +
                     (nbase + c0) * 16 + g * 4] = o;
    }
    __syncthreads();
  }
}

// ---------------------------------------------------------------------------
// Window aggregation, 4 vertically-adjacent pixels per thread (unchanged).
// ---------------------------------------------------------------------------
__global__ __launch_bounds__(256) void aggregate_kernel(
    const __bf16* __restrict__ v, const float* __restrict__ attn,
    __bf16* __restrict__ y) {
  const int idx = blockIdx.x * 256 + threadIdx.x;  // NPIX/4 * 48 = 602112
  const int cg = idx % 48;
  const int pg = idx / 48;
  const int c  = cg * 8;
  const int b  = pg / ((HH / 4) * WW);
  const int r2 = pg % ((HH / 4) * WW);
  const int i0 = (r2 / WW) * 4;
  const int j  = r2 % WW;
  const int head = c >> 6;

  const int pbase = (b * HH + i0) * WW + j;
  float aw[4][9];
  #pragma unroll
  for (int p = 0; p < 4; ++p) {
    const float* ap = attn + (size_t)(pbase + p * WW) * NLOGIT + head * 9;
    #pragma unroll
    for (int w = 0; w < 9; ++w) aw[p][w] = ap[w];
  }

  const bool j0ok = (j > 0), j2ok = (j < WW - 1);
  float acc[4][8] = {};

  #pragma unroll
  for (int li = 0; li < 6; ++li) {
    const int ii = i0 - 1 + li;
    if (ii < 0 || ii >= HH) continue;
    const __bf16* vrow = v + ((size_t)(b * HH + ii) * WW + j) * CDIM + c;
    float ch[3][8];
    #pragma unroll
    for (int kj = 0; kj < 3; ++kj) {
      const bool ok = (kj == 0) ? j0ok : (kj == 2) ? j2ok : true;
      if (ok) {
        const bf16x8 vv = *(const bf16x8*)(vrow + (kj - 1) * CDIM);
        #pragma unroll
        for (int q = 0; q < 8; ++q) ch[kj][q] = (float)vv[q];
      } else {
        #pragma unroll
        for (int q = 0; q < 8; ++q) ch[kj][q] = 0.f;
      }
    }
    #pragma unroll
    for (int p = 0; p < 4; ++p) {
      const int ki = li - p;
      if (ki < 0 || ki > 2) continue;
      #pragma unroll
      for (int kj = 0; kj < 3; ++kj) {
        const float w = aw[p][ki * 3 + kj];
        #pragma unroll
        for (int q = 0; q < 8; ++q) acc[p][q] += w * ch[kj][q];
      }
    }
  }

  #pragma unroll
  for (int p = 0; p < 4; ++p) {
    bf16x8 o;
    #pragma unroll
    for (int q = 0; q < 8; ++q) o[q] = (__bf16)acc[p][q];
    *(bf16x8*)&y[(size_t)(pbase + p * WW) * CDIM + c] = o;
  }
}

// ---------------------------------------------------------------------------
extern "C" void kernel_launch(void* const* d_in, const int* in_sizes, int n_in,
                              void* d_out, int out_size, void* d_ws,
                              size_t ws_size, hipStream_t stream) {
  const float* x      = (const float*)d_in[0];
  const float* W_attn = (const float*)d_in[1];
  const float* b_attn = (const float*)d_in[2];
  const float* W_v    = (const float*)d_in[3];
  const float* b_v    = (const float*)d_in[4];
  const float* W_proj = (const float*)d_in[5];
  const float* b_proj = (const float*)d_in[6];
  float* out = (float*)d_out;

  char* w = (char*)d_ws;
  __bf16* v    = (__bf16*)w;  w += (size_t)NPIX * CDIM * 2;   // 38.5MB
  __bf16* y    = (__bf16*)w;  w += (size_t)NPIX * CDIM * 2;   // 38.5MB
  float*  attn = (float*)w;   w += (size_t)NPIX * NLOGIT * 4; // 10.8MB
  __bf16* Wcat_frag = (__bf16*)w;  w += (size_t)(NCH_V * 16) * CDIM * 2;
  __bf16* Wtp_frag  = (__bf16*)w;  w += (size_t)CDIM * CDIM * 2;
  float*  bpad = (float*)w;   w += 64 * 4;

  // prep: fragment-major weights
  const int prep_n = KSTEPS * NCH_V * 64 + KSTEPS * NCH_P * 64 + 64;
  prep_kernel<<<(prep_n + 255) / 256, 256, 0, stream>>>(
      W_v, W_proj, W_attn, b_attn, Wcat_frag, Wtp_frag, bpad);

  // 1. merged v-GEMM + logits/softmax (fp32 A in-kernel, r13 schedule)
  gemm_v_logit_kernel<<<dim3(NPIX / 64, 2), 256, 0, stream>>>(
      x, Wcat_frag, b_v, v, bpad, attn);

  // 2. window aggregation -> y (bf16), 4 px/thread
  aggregate_kernel<<<(NPIX / 4 * 48) / 256, 256, 0, stream>>>(v, attn, y);

  // 3. out = y @ Wtp^T + b_proj (fp32 out, r13 schedule)
  gemm_proj_kernel<<<dim3(NPIX / 64, 2), 256, 0, stream>>>(
      y, Wtp_frag, b_proj, out);
}

// Round 22
// 109.799 us; speedup vs baseline: 4.0958x; 4.0958x over previous
//
#include <hip/hip_runtime.h>
#include <math.h>

#define NPIX 50176      // 16*56*56
#define CDIM 384
#define HEADS 6
#define NLOGIT 54       // HEADS*9
#define HH 56
#define WW 56
#define NCAT 448        // 384 v-cols + 64 padded logit cols
#define KSTEPS 12       // CDIM/32
#define NCH_V 28        // NCAT/16 fragment chunks (total)
#define NCH_P 24        // CDIM/16 fragment chunks (total)

typedef __attribute__((ext_vector_type(8))) __bf16 bf16x8;
typedef __attribute__((ext_vector_type(4))) float f32x4;

__device__ __forceinline__ void glds16(const void* g, void* l) {
  __builtin_amdgcn_global_load_lds(
      (const __attribute__((address_space(1))) unsigned int*)g,
      (__attribute__((address_space(3))) unsigned int*)l, 16, 0, 0);
}

// ---------------------------------------------------------------------------
// Prep: fragment-major weights.
// Wcat_frag chunk (ks, ni, lane): 8 bf16 of B^T[n=ni*16+(lane&15)]
//   [k=ks*32+(lane>>4)*8+q]; n<384 = W_v, 384+nn<54 = W_attn, else 0.
// Wtp_frag likewise for W_proj. bpad[64].
// ---------------------------------------------------------------------------
__global__ __launch_bounds__(256) void prep_kernel(
    const float* __restrict__ W_v, const float* __restrict__ W_proj,
    const float* __restrict__ W_attn, const float* __restrict__ b_attn,
    __bf16* __restrict__ Wcat_frag, __bf16* __restrict__ Wtp_frag,
    float* __restrict__ bpad) {
  const int gid = blockIdx.x * 256 + threadIdx.x;
  const int NV = KSTEPS * NCH_V * 64;   // 21504
  const int NP = KSTEPS * NCH_P * 64;   // 18432
  if (gid < NV) {
    const int ks   = gid / (NCH_V * 64);
    const int rem  = gid % (NCH_V * 64);
    const int ni   = rem >> 6;
    const int lane = rem & 63;
    const int n  = ni * 16 + (lane & 15);
    const int kb = ks * 32 + (lane >> 4) * 8;
    bf16x8 o;
    #pragma unroll
    for (int q = 0; q < 8; ++q) {
      const int k = kb + q;
      float val;
      if (n < CDIM) val = W_v[k * CDIM + n];
      else {
        const int nn = n - CDIM;
        val = (nn < NLOGIT) ? W_attn[k * NLOGIT + nn] : 0.f;
      }
      o[q] = (__bf16)val;
    }
    *(bf16x8*)&Wcat_frag[(size_t)gid * 8] = o;
  } else if (gid < NV + NP) {
    const int r    = gid - NV;
    const int ks   = r / (NCH_P * 64);
    const int rem  = r % (NCH_P * 64);
    const int ni   = rem >> 6;
    const int lane = rem & 63;
    const int n  = ni * 16 + (lane & 15);
    const int kb = ks * 32 + (lane >> 4) * 8;
    bf16x8 o;
    #pragma unroll
    for (int q = 0; q < 8; ++q) o[q] = (__bf16)W_proj[(kb + q) * CDIM + n];
    *(bf16x8*)&Wtp_frag[(size_t)r * 8] = o;
  } else if (gid < NV + NP + 64) {
    const int n = gid - NV - NP;
    bpad[n] = (n < NLOGIT) ? b_attn[n] : 0.f;
  }
}

// ---------------------------------------------------------------------------
// Merged GEMM, N split in half: grid (NPIX/64, 2). Block by owns 14 chunks
// (cols by*224 .. +224). Double-buffered B-stage: glds16 for ks+1 issued
// before the MFMA phase of ks. acc[14] (56 regs).
// by==1 chunks 10..13 are the logit cols -> softmax -> attn.
// ---------------------------------------------------------------------------
__global__ __launch_bounds__(256) void gemm_v_logit_kernel(
    const float* __restrict__ X, const __bf16* __restrict__ Wcat_frag,
    const float* __restrict__ b_v, __bf16* __restrict__ v,
    const float* __restrict__ bpad, float* __restrict__ attn) {
  __shared__ char smem[2 * 14 * 1024];           // 28672B: 2 x 14-chunk buf
  float (*Ls)[68] = (float(*)[68])smem;          // overlay (17408B)

  const int tid  = threadIdx.x;
  const int wave = tid >> 6;
  const int lane = tid & 63;
  const int bm   = blockIdx.x * 64;
  const int by   = blockIdx.y;                   // 0 or 1
  const int nbase = by * 14;                     // chunk offset
  const int frow = lane & 15;
  const int fk8  = (lane >> 4) * 8;

  const int arow = bm + wave * 16 + frow;
  const float* xrow = X + (size_t)arow * CDIM + fk8;

  f32x4 acc[14] = {};

  // prologue: stage ks=0 into buf0, prefetch A(0)
  #pragma unroll
  for (int c = 0; c < 4; ++c) {
    const int chunk = wave * 4 + c;
    if (chunk < 14)
      glds16(Wcat_frag + ((size_t)(0 * NCH_V + nbase + chunk) * 64 + lane) * 8,
             (__bf16*)smem + chunk * 512);
  }
  float4 pa0 = *(const float4*)(xrow + 0);
  float4 pa1 = *(const float4*)(xrow + 4);
  __syncthreads();

  int buf = 0;
  for (int ks = 0; ks < KSTEPS; ++ks) {
    // issue next-step B stage into the other buffer (async, overlaps MFMA)
    if (ks + 1 < KSTEPS) {
      __bf16* dst = (__bf16*)smem + (buf ^ 1) * 14 * 512;
      #pragma unroll
      for (int c = 0; c < 4; ++c) {
        const int chunk = wave * 4 + c;
        if (chunk < 14)
          glds16(Wcat_frag +
                     ((size_t)((ks + 1) * NCH_V + nbase + chunk) * 64 + lane) * 8,
                 dst + chunk * 512);
      }
    }
    // convert prefetched A; prefetch next
    bf16x8 a;
    a[0] = (__bf16)pa0.x; a[1] = (__bf16)pa0.y; a[2] = (__bf16)pa0.z; a[3] = (__bf16)pa0.w;
    a[4] = (__bf16)pa1.x; a[5] = (__bf16)pa1.y; a[6] = (__bf16)pa1.z; a[7] = (__bf16)pa1.w;
    if (ks + 1 < KSTEPS) {
      pa0 = *(const float4*)(xrow + (ks + 1) * 32 + 0);
      pa1 = *(const float4*)(xrow + (ks + 1) * 32 + 4);
    }

    const __bf16* Bc = (const __bf16*)smem + buf * 14 * 512;
    #pragma unroll
    for (int ni = 0; ni < 14; ++ni) {
      const bf16x8 b = *(const bf16x8*)&Bc[(ni * 64 + lane) * 8];
      acc[ni] = __builtin_amdgcn_mfma_f32_16x16x32_bf16(a, b, acc[ni], 0, 0, 0);
    }
    __syncthreads();   // drains next-step glds16 (overlapped) + read fence
    buf ^= 1;
  }

  const int orow = (lane >> 4) * 4;
  const int nv = (by == 0) ? 14 : 10;   // v chunks this block

  #pragma unroll
  for (int ni = 0; ni < 14; ++ni) {
    if (ni < nv) {
      const int n = by * 224 + ni * 16 + frow;
      const float bvl = b_v[n];
      #pragma unroll
      for (int r = 0; r < 4; ++r) {
        const int m = bm + wave * 16 + orow + r;
        v[(size_t)m * CDIM + n] = (__bf16)(acc[ni][r] + bvl);
      }
    }
  }

  if (by == 1) {
    // logit chunks 10..13 -> Ls -> softmax -> attn
    float bvl[4];
    #pragma unroll
    for (int ni = 0; ni < 4; ++ni) bvl[ni] = bpad[ni * 16 + frow];
    #pragma unroll
    for (int ni = 0; ni < 4; ++ni)
      #pragma unroll
      for (int r = 0; r < 4; ++r)
        Ls[wave * 16 + orow + r][ni * 16 + frow] = acc[10 + ni][r] + bvl[ni];
    __syncthreads();

    #pragma unroll
    for (int it = 0; it < 2; ++it) {
      const int task = it * 256 + tid;
      if (task < 64 * HEADS) {
        const int pl = task / HEADS;
        const int h  = task % HEADS;
        const float* row = &Ls[pl][h * 9];
        float m = row[0];
        #pragma unroll
        for (int w = 1; w < 9; ++w) m = fmaxf(m, row[w]);
        float e[9], s = 0.f;
        #pragma unroll
        for (int w = 0; w < 9; ++w) { e[w] = __expf(row[w] - m); s += e[w]; }
        const float inv = 1.f / s;
        float* op = &attn[(size_t)(bm + pl) * NLOGIT + h * 9];
        #pragma unroll
        for (int w = 0; w < 9; ++w) op[w] = e[w] * inv;
      }
    }
  }
}

// ---------------------------------------------------------------------------
// Proj GEMM, N split in half: grid (NPIX/64, 2), 12 chunks each, dbuf.
// A (y bf16) per-lane from global, prefetched. Out fp32.
// ---------------------------------------------------------------------------
__global__ __launch_bounds__(256) void gemm_proj_kernel(
    const __bf16* __restrict__ Y, const __bf16* __restrict__ Wtp_frag,
    const float* __restrict__ bias, float* __restrict__ Out) {
  __shared__ __bf16 Bs[2 * 12 * 512];   // 24576B

  const int tid  = threadIdx.x;
  const int wave = tid >> 6;
  const int lane = tid & 63;
  const int bm   = blockIdx.x * 64;
  const int by   = blockIdx.y;
  const int nbase = by * 12;
  const int frow = lane & 15;
  const int fk8  = (lane >> 4) * 8;

  const int arow = bm + wave * 16 + frow;
  const __bf16* yrow = Y + (size_t)arow * CDIM + fk8;

  f32x4 acc[12] = {};

  #pragma unroll
  for (int c = 0; c < 3; ++c) {
    const int chunk = wave * 3 + c;
    glds16(Wtp_frag + ((size_t)(nbase + chunk) * 64 + lane) * 8,
           Bs + chunk * 512);
  }
  bf16x8 a = *(const bf16x8*)(yrow);
  __syncthreads();

  int buf = 0;
  for (int ks = 0; ks < KSTEPS; ++ks) {
    if (ks + 1 < KSTEPS) {
      __bf16* dst = Bs + (buf ^ 1) * 12 * 512;
      #pragma unroll
      for (int c = 0; c < 3; ++c) {
        const int chunk = wave * 3 + c;
        glds16(Wtp_frag +
                   ((size_t)((ks + 1) * NCH_P + nbase + chunk) * 64 + lane) * 8,
               dst + chunk * 512);
      }
    }
    bf16x8 a_next;
    if (ks + 1 < KSTEPS) a_next = *(const bf16x8*)(yrow + (ks + 1) * 32);

    const __bf16* Bc = Bs + buf * 12 * 512;
    #pragma unroll
    for (int ni = 0; ni < 12; ++ni) {
      const bf16x8 b = *(const bf16x8*)&Bc[(ni * 64 + lane) * 8];
      acc[ni] = __builtin_amdgcn_mfma_f32_16x16x32_bf16(a, b, acc[ni], 0, 0, 0);
    }
    __syncthreads();
    buf ^= 1;
    a = a_next;
  }

  const int orow = (lane >> 4) * 4;
  #pragma unroll
  for (int ni = 0; ni < 12; ++ni) {
    const int n = by * 192 + ni * 16 + frow;
    const float bvl = bias[n];
    #pragma unroll
    for (int r = 0; r < 4; ++r) {
      const int m = bm + wave * 16 + orow + r;
      Out[(size_t)m * CDIM + n] = acc[ni][r] + bvl;
    }
  }
}

// ---------------------------------------------------------------------------
// Window aggregation, 4 vertically-adjacent pixels per thread (unchanged).
// ---------------------------------------------------------------------------
__global__ __launch_bounds__(256) void aggregate_kernel(
    const __bf16* __restrict__ v, const float* __restrict__ attn,
    __bf16* __restrict__ y) {
  const int idx = blockIdx.x * 256 + threadIdx.x;  // NPIX/4 * 48 = 602112
  const int cg = idx % 48;
  const int pg = idx / 48;
  const int c  = cg * 8;
  const int b  = pg / ((HH / 4) * WW);
  const int r2 = pg % ((HH / 4) * WW);
  const int i0 = (r2 / WW) * 4;
  const int j  = r2 % WW;
  const int head = c >> 6;

  const int pbase = (b * HH + i0) * WW + j;
  float aw[4][9];
  #pragma unroll
  for (int p = 0; p < 4; ++p) {
    const float* ap = attn + (size_t)(pbase + p * WW) * NLOGIT + head * 9;
    #pragma unroll
    for (int w = 0; w < 9; ++w) aw[p][w] = ap[w];
  }

  const bool j0ok = (j > 0), j2ok = (j < WW - 1);
  float acc[4][8] = {};

  #pragma unroll
  for (int li = 0; li < 6; ++li) {
    const int ii = i0 - 1 + li;
    if (ii < 0 || ii >= HH) continue;
    const __bf16* vrow = v + ((size_t)(b * HH + ii) * WW + j) * CDIM + c;
    float ch[3][8];
    #pragma unroll
    for (int kj = 0; kj < 3; ++kj) {
      const bool ok = (kj == 0) ? j0ok : (kj == 2) ? j2ok : true;
      if (ok) {
        const bf16x8 vv = *(const bf16x8*)(vrow + (kj - 1) * CDIM);
        #pragma unroll
        for (int q = 0; q < 8; ++q) ch[kj][q] = (float)vv[q];
      } else {
        #pragma unroll
        for (int q = 0; q < 8; ++q) ch[kj][q] = 0.f;
      }
    }
    #pragma unroll
    for (int p = 0; p < 4; ++p) {
      const int ki = li - p;
      if (ki < 0 || ki > 2) continue;
      #pragma unroll
      for (int kj = 0; kj < 3; ++kj) {
        const float w = aw[p][ki * 3 + kj];
        #pragma unroll
        for (int q = 0; q < 8; ++q) acc[p][q] += w * ch[kj][q];
      }
    }
  }

  #pragma unroll
  for (int p = 0; p < 4; ++p) {
    bf16x8 o;
    #pragma unroll
    for (int q = 0; q < 8; ++q) o[q] = (__bf16)acc[p][q];
    *(bf16x8*)&y[(size_t)(pbase + p * WW) * CDIM + c] = o;
  }
}

// ---------------------------------------------------------------------------
extern "C" void kernel_launch(void* const* d_in, const int* in_sizes, int n_in,
                              void* d_out, int out_size, void* d_ws,
                              size_t ws_size, hipStream_t stream) {
  const float* x      = (const float*)d_in[0];
  const float* W_attn = (const float*)d_in[1];
  const float* b_attn = (const float*)d_in[2];
  const float* W_v    = (const float*)d_in[3];
  const float* b_v    = (const float*)d_in[4];
  const float* W_proj = (const float*)d_in[5];
  const float* b_proj = (const float*)d_in[6];
  float* out = (float*)d_out;

  char* w = (char*)d_ws;
  __bf16* v    = (__bf16*)w;  w += (size_t)NPIX * CDIM * 2;   // 38.5MB
  __bf16* y    = (__bf16*)w;  w += (size_t)NPIX * CDIM * 2;   // 38.5MB
  float*  attn = (float*)w;   w += (size_t)NPIX * NLOGIT * 4; // 10.8MB
  __bf16* Wcat_frag = (__bf16*)w;  w += (size_t)NCAT * CDIM * 2;  // 344KB
  __bf16* Wtp_frag  = (__bf16*)w;  w += (size_t)CDIM * CDIM * 2;  // 288KB
  float*  bpad = (float*)w;   w += 64 * 4;

  // prep (one dispatch): fragment-major weights
  const int prep_n = KSTEPS * NCH_V * 64 + KSTEPS * NCH_P * 64 + 64;
  prep_kernel<<<(prep_n + 255) / 256, 256, 0, stream>>>(
      W_v, W_proj, W_attn, b_attn, Wcat_frag, Wtp_frag, bpad);

  // 1. merged split-N: v-GEMM + logits/softmax
  gemm_v_logit_kernel<<<dim3(NPIX / 64, 2), 256, 0, stream>>>(
      x, Wcat_frag, b_v, v, bpad, attn);

  // 2. window aggregation -> y (bf16), 4 px/thread
  aggregate_kernel<<<(NPIX / 4 * 48) / 256, 256, 0, stream>>>(v, attn, y);

  // 3. out = y @ Wtp^T + b_proj (fp32 out), split-N, dbuf
  gemm_proj_kernel<<<dim3(NPIX / 64, 2), 256, 0, stream>>>(
      y, Wtp_frag, b_proj, out);
}